// Round 8
// baseline (526.342 us; speedup 1.0000x reference)
//
#include <hip/hip_runtime.h>
#include <hip/hip_bf16.h>
#include <math.h>

typedef __hip_bfloat16 bf16;
typedef unsigned short ushort_t;
typedef __bf16 bf16x8 __attribute__((ext_vector_type(8)));
typedef unsigned short ushortx8 __attribute__((ext_vector_type(8)));
typedef float  f32x4  __attribute__((ext_vector_type(4)));

#define BATCH 8
#define HH 112
#define WW 112
#define CDIM 192
#define HEADS 6
#define HD 32
#define QKVW 576
#define MLPW 768
#define WS 7
#define WS2 49
#define NWH 16
#define NWW 16
#define NWIN 256
#define NTOK (BATCH*HH*WW)   // 100352
#define NEGV (-1e9f)

typedef __attribute__((address_space(3))) void lds_void;
typedef const __attribute__((address_space(1))) void gbl_void;

__device__ __forceinline__ float toF(float v) { return v; }
__device__ __forceinline__ float toF(bf16 v) { return __bfloat162float(v); }
__device__ __forceinline__ bf16  f2b(float v) { return __float2bfloat16(v); }
__device__ __forceinline__ ushort_t f2u(float v) { bf16 b = __float2bfloat16(v); return *(ushort_t*)&b; }

// Per-array dtype probe (first 16 words). Deterministic.
__device__ __forceinline__ bool probe_is_bf16(const void* p) {
    const unsigned int* w = (const unsigned int*)p;
    int nz = 0, band = 0;
    #pragma unroll
    for (int i = 0; i < 16; i++) {
        unsigned int v = w[i];
        if (v == 0u) continue;
        nz++;
        unsigned int lo = v & 0xFFFFu, hi = v >> 16;
        unsigned int elo = (lo >> 7) & 0xFFu, ehi = (hi >> 7) & 0xFFu;
        bool okl = (lo != 0u) && (elo >= 0x60u) && (elo <= 0x9Fu);
        bool okh = (hi != 0u) && (ehi >= 0x60u) && (ehi <= 0x9Fu);
        if (okl && okh) band++;
    }
    return (nz == 0) || (band == nz);
}

__device__ __forceinline__ float read_any(const void* p, size_t i, bool isb) {
    return isb ? toF(((const bf16*)p)[i]) : ((const float*)p)[i];
}

// ---------------- Fused canon of all 8 small fp32 params (1 launch) ----------------
__global__ void canon_small_kernel(const void* s0, const void* s1, const void* s2,
                                   const void* s3, const void* s4, const void* s5,
                                   const void* s6, const void* s7,
                                   float* __restrict__ cW) {
    const void* srcs[8] = {s0, s1, s2, s3, s4, s5, s6, s7};
    const int off[8]  = {0, 192, 361, 553, 745, 937, 1129, 1897};
    const int cnt[8]  = {192, 169, 192, 192, 192, 192, 768, 192};
    const int doff[8] = {0, 192, 384, 576, 768, 960, 1152, 1920};
    int i = blockIdx.x * 256 + threadIdx.x;
    if (i >= 2089) return;
    int s = 0;
    #pragma unroll
    for (int k = 1; k < 8; k++) if (i >= off[k]) s = k;
    int j = i - off[s];
    if (j < cnt[s]) {
        bool isb = probe_is_bf16(srcs[s]);
        cW[doff[s] + j] = read_any(srcs[s], j, isb);
    }
}

// ---------------- Fused canon+transpose of all 4 weights (1 launch) ----------------
__global__ void canon_bt4_kernel(const void* w0, const void* w1, const void* w2,
                                 const void* w3, ushort_t* __restrict__ cT) {
    int bid = blockIdx.x;
    const void* src; ushort_t* dst; int K, N, base;
    if (bid < 432)       { src = w0; dst = cT;          K = CDIM; N = QKVW; base = bid; }
    else if (bid < 576)  { src = w1; dst = cT + 110592; K = CDIM; N = CDIM; base = bid - 432; }
    else if (bid < 1152) { src = w2; dst = cT + 147456; K = CDIM; N = MLPW; base = bid - 576; }
    else                 { src = w3; dst = cT + 294912; K = MLPW; N = CDIM; base = bid - 1152; }
    int i = base * 256 + threadIdx.x;
    if (i < K * N) {
        bool isb = probe_is_bf16(src);
        int k = i / N, n = i % N;
        dst[(size_t)n * K + k] = f2u(read_any(src, i, isb));
    }
}

// ========== Reg-A MFMA GEMM for K=192 (+ fused LN1 / epilogues) ==========
// Key exploit: A is token-major [tok][192], so the MFMA A-fragment
// [l15=row][quad*8+j=k] loads DIRECTLY from global as one bf16x8/lane —
// no A-side LDS at all (same trick as attn's Q/K). Only B (the weight) is
// staged: 24 KB via global_load_lds w16 + both-sides XOR swizzle, issued
// FIRST so its latency hides under the A/LN register work. ONE barrier.
// Wave owns 32 rows (2 M-tiles): each B-fragment read feeds 2 MFMAs.
// EPI 0: A = LN1(raw x, probed fp32/bf16) computed in registers (stats
//        reduced across quads via shfl_xor 16/32) -> qkv, plain bf16 store.
//        LN1 recomputed per y-block (9x); x re-reads are L2 hits (y-fastest
//        XCD-chunked block order). Kills ln1 kernel + bufA round-trip.
// EPI 1: A = bufY bf16 direct; +bias +probed-x residual -> bf16 (proj).
// VGPR discipline (round-5 lesson): LN processed one M-tile at a time so
// the fp32-path temp (48 VGPR) never coexists across tiles. No min-wave
// launch-bounds clamp (the (512,4) clamp caused a 1.5 GB spill in round 5).
template <int EPI, int NY>
__global__ __launch_bounds__(256) void gemm192f_kernel(
    const void* __restrict__ Araw,   // EPI0: raw x (probed); EPI1: bufY bf16
    const ushort_t* __restrict__ BT, // [N][192] bf16
    const int N,
    const float* __restrict__ g, const float* __restrict__ bta,  // EPI0
    const float* __restrict__ bias,                               // EPI1
    const void* __restrict__ res,                                 // EPI1
    void* __restrict__ out)
{
    __shared__ ushort_t Bs[3][64 * 64];
    int tid = threadIdx.x;
    int per = gridDim.x >> 3;
    int sid = blockIdx.x;
    int w = (sid & 7) * per + (sid >> 3);
    int t0 = (w / NY) * 128;
    int n0 = (w % NY) * 64;
    int lane = tid & 63, wv = tid >> 6;
    int l15 = lane & 15, quad = lane >> 4;
    int lr = lane >> 3, lc = lane & 7;

    // ---- stage B first (3 panels [64][64], 6 instr/thread-wave) ----
    #pragma unroll
    for (int p = 0; p < 3; p++) {
        #pragma unroll
        for (int it = 0; it < 2; it++) {
            int r = wv * 16 + it * 8 + lr;                 // r&7 == lr
            const ushort_t* src = &BT[(size_t)(n0 + r) * 192 + p * 64 + ((lc ^ lr) << 3)];
            __builtin_amdgcn_global_load_lds(
                (gbl_void*)src, (lds_void*)&Bs[p][(wv * 16 + it * 8) * 64], 16, 0, 0);
        }
    }

    // ---- A fragments in registers ----
    bf16x8 af[2][6];
    if (EPI == 0) {
        bool xb = probe_is_bf16(Araw);
        if (xb) {
            const ushort_t* xh = (const ushort_t*)Araw;
            #pragma unroll
            for (int m = 0; m < 2; m++) {
                size_t rb = (size_t)(t0 + wv * 32 + m * 16 + l15) * CDIM;
                float s = 0.f, s2 = 0.f;
                #pragma unroll
                for (int kk = 0; kk < 6; kk++) {
                    af[m][kk] = *(const bf16x8*)(xh + rb + kk * 32 + quad * 8);
                    #pragma unroll
                    for (int j = 0; j < 8; j++) {
                        float f = (float)af[m][kk][j];
                        s += f; s2 += f * f;
                    }
                }
                s  += __shfl_xor(s, 16, 64);  s  += __shfl_xor(s, 32, 64);
                s2 += __shfl_xor(s2, 16, 64); s2 += __shfl_xor(s2, 32, 64);
                float mu = s * (1.0f / CDIM);
                float rs = rsqrtf(s2 * (1.0f / CDIM) - mu * mu + 1e-5f);
                #pragma unroll
                for (int kk = 0; kk < 6; kk++) {
                    int c0 = kk * 32 + quad * 8;
                    float4 g0 = *(const float4*)(g + c0), g1 = *(const float4*)(g + c0 + 4);
                    float4 b0 = *(const float4*)(bta + c0), b1v = *(const float4*)(bta + c0 + 4);
                    const float* gp[2] = {&g0.x, &g1.x};
                    const float* bp[2] = {&b0.x, &b1v.x};
                    #pragma unroll
                    for (int j = 0; j < 8; j++)
                        af[m][kk][j] = (__bf16)(((float)af[m][kk][j] - mu) * rs * gp[j >> 2][j & 3]
                                                + bp[j >> 2][j & 3]);
                }
            }
        } else {
            const float* xf = (const float*)Araw;
            #pragma unroll
            for (int m = 0; m < 2; m++) {
                size_t rb = (size_t)(t0 + wv * 32 + m * 16 + l15) * CDIM;
                float va[6][8];
                float s = 0.f, s2 = 0.f;
                #pragma unroll
                for (int kk = 0; kk < 6; kk++) {
                    float4 a0 = *(const float4*)(xf + rb + kk * 32 + quad * 8);
                    float4 a1 = *(const float4*)(xf + rb + kk * 32 + quad * 8 + 4);
                    va[kk][0] = a0.x; va[kk][1] = a0.y; va[kk][2] = a0.z; va[kk][3] = a0.w;
                    va[kk][4] = a1.x; va[kk][5] = a1.y; va[kk][6] = a1.z; va[kk][7] = a1.w;
                    #pragma unroll
                    for (int j = 0; j < 8; j++) { s += va[kk][j]; s2 += va[kk][j] * va[kk][j]; }
                }
                s  += __shfl_xor(s, 16, 64);  s  += __shfl_xor(s, 32, 64);
                s2 += __shfl_xor(s2, 16, 64); s2 += __shfl_xor(s2, 32, 64);
                float mu = s * (1.0f / CDIM);
                float rs = rsqrtf(s2 * (1.0f / CDIM) - mu * mu + 1e-5f);
                #pragma unroll
                for (int kk = 0; kk < 6; kk++) {
                    int c0 = kk * 32 + quad * 8;
                    float4 g0 = *(const float4*)(g + c0), g1 = *(const float4*)(g + c0 + 4);
                    float4 b0 = *(const float4*)(bta + c0), b1v = *(const float4*)(bta + c0 + 4);
                    const float* gp[2] = {&g0.x, &g1.x};
                    const float* bp[2] = {&b0.x, &b1v.x};
                    #pragma unroll
                    for (int j = 0; j < 8; j++)
                        af[m][kk][j] = (__bf16)((va[kk][j] - mu) * rs * gp[j >> 2][j & 3]
                                                + bp[j >> 2][j & 3]);
                }
            }
        }
    } else {
        const ushort_t* ah = (const ushort_t*)Araw;
        #pragma unroll
        for (int m = 0; m < 2; m++) {
            size_t rb = (size_t)(t0 + wv * 32 + m * 16 + l15) * CDIM;
            #pragma unroll
            for (int kk = 0; kk < 6; kk++)
                af[m][kk] = *(const bf16x8*)(ah + rb + kk * 32 + quad * 8);
        }
    }

    f32x4 acc[2][4];
    #pragma unroll
    for (int i = 0; i < 2; i++)
        #pragma unroll
        for (int j = 0; j < 4; j++)
            acc[i][j] = (f32x4){0.f, 0.f, 0.f, 0.f};

    __syncthreads();    // Bs resident (drains global_load_lds)

    #pragma unroll
    for (int kk = 0; kk < 6; kk++) {
        int p = kk >> 1;
        int cs = ((((kk & 1) * 4 + quad)) ^ (l15 & 7)) << 3;
        bf16x8 bfr[4];
        #pragma unroll
        for (int j = 0; j < 4; j++)
            bfr[j] = *(const bf16x8*)(&Bs[p][(j * 16 + l15) * 64 + cs]);
        #pragma unroll
        for (int i = 0; i < 2; i++)
            #pragma unroll
            for (int j = 0; j < 4; j++)
                acc[i][j] = __builtin_amdgcn_mfma_f32_16x16x32_bf16(af[i][kk], bfr[j], acc[i][j], 0, 0, 0);
    }

    bool xb = false;
    if (EPI == 1) xb = probe_is_bf16(res);

    #pragma unroll
    for (int i = 0; i < 2; i++) {
        #pragma unroll
        for (int j = 0; j < 4; j++) {
            #pragma unroll
            for (int r = 0; r < 4; r++) {
                int row = wv * 32 + i * 16 + quad * 4 + r;
                int col = n0 + j * 16 + l15;
                size_t t = (size_t)(t0 + row);
                float v = acc[i][j][r];
                if (EPI == 0) {
                    ((bf16*)out)[t * N + col] = f2b(v);
                } else {
                    size_t o = t * CDIM + col;
                    ((bf16*)out)[o] = f2b(v + bias[col] + read_any(res, o, xb));
                }
            }
        }
    }
}

// ================= Fused LN2 + MLP1(+GELU) + MLP2 (+residual), v5 =================
// Round-4 structure (measured 164->157us, VGPR 128, no spill): block = 256 thr
// = 4 waves = 128 tokens, wave owns 32 rows (2 M-tiles), LDS 64 KB, 2 blocks/CU.
// __launch_bounds__(256,2): VGPR cap 256 — fat-wave working set needs ~200.
__global__ __launch_bounds__(256, 2) void fused_mlp_kernel(
    const bf16* __restrict__ X,        // [NTOK][192] bf16 (pre-LN residual = x1)
    const ushort_t* __restrict__ W1T,  // [768][192]
    const ushort_t* __restrict__ W2T,  // [192][768]
    const float* __restrict__ g, const float* __restrict__ bta,
    const float* __restrict__ b1, const float* __restrict__ b2,
    float* __restrict__ out)
{
    __shared__ ushort_t W1s[3 * 64 * 64];   // (24 KB)
    __shared__ ushort_t W2s[192 * 64];      // (24 KB)
    __shared__ ushort_t Hs[128 * 64];       // (16 KB)
    int tid = threadIdx.x;
    int lane = tid & 63, wv = tid >> 6;     // wv 0..3
    int l15 = lane & 15, quad = lane >> 4;
    int lr = lane >> 3, lc = lane & 7;
    int t0 = blockIdx.x * 128;

    auto stageW1 = [&](int c) {
        #pragma unroll
        for (int p = 0; p < 3; p++)
            #pragma unroll
            for (int rg = 0; rg < 2; rg++) {
                int rowb = wv * 16 + rg * 8;
                const ushort_t* src =
                    &W1T[(size_t)(c * 64 + rowb + lr) * CDIM + p * 64 + ((lc ^ lr) << 3)];
                __builtin_amdgcn_global_load_lds(
                    (gbl_void*)src, (lds_void*)&W1s[p * 4096 + rowb * 64], 16, 0, 0);
            }
    };
    auto stageW2 = [&](int c) {
        #pragma unroll
        for (int rg = 0; rg < 6; rg++) {
            int rowb = wv * 48 + rg * 8;
            const ushort_t* src =
                &W2T[(size_t)(rowb + lr) * MLPW + c * 64 + ((lc ^ lr) << 3)];
            __builtin_amdgcn_global_load_lds(
                (gbl_void*)src, (lds_void*)&W2s[rowb * 64], 16, 0, 0);
        }
    };

    stageW1(0);
    stageW2(0);

    // ---- LN2 into register A-fragments, in place (wave's 2 x 16 rows) ----
    bf16x8 af[2][6];
    float s[2] = {0.f, 0.f}, s2[2] = {0.f, 0.f};
    #pragma unroll
    for (int m = 0; m < 2; m++) {
        size_t rb = (size_t)(t0 + wv * 32 + m * 16 + l15) * CDIM;
        #pragma unroll
        for (int kk = 0; kk < 6; kk++) {
            af[m][kk] = *(const bf16x8*)((const ushort_t*)X + rb + kk * 32 + quad * 8);
            #pragma unroll
            for (int j = 0; j < 8; j++) {
                float f = (float)af[m][kk][j];
                s[m] += f; s2[m] += f * f;
            }
        }
    }
    #pragma unroll
    for (int m = 0; m < 2; m++) {
        s[m]  += __shfl_xor(s[m], 16, 64);  s[m]  += __shfl_xor(s[m], 32, 64);
        s2[m] += __shfl_xor(s2[m], 16, 64); s2[m] += __shfl_xor(s2[m], 32, 64);
    }
    #pragma unroll
    for (int kk = 0; kk < 6; kk++) {
        int c0 = kk * 32 + quad * 8;
        float4 g0 = *(const float4*)(g + c0), g1 = *(const float4*)(g + c0 + 4);
        float4 b0 = *(const float4*)(bta + c0), b1v = *(const float4*)(bta + c0 + 4);
        const float* gp[2] = {&g0.x, &g1.x};
        const float* bp[2] = {&b0.x, &b1v.x};
        #pragma unroll
        for (int m = 0; m < 2; m++) {
            float mu = s[m] * (1.0f / CDIM);
            float var = s2[m] * (1.0f / CDIM) - mu * mu;
            float rs = rsqrtf(var + 1e-5f);
            #pragma unroll
            for (int j = 0; j < 8; j++)
                af[m][kk][j] = (__bf16)(((float)af[m][kk][j] - mu) * rs * gp[j >> 2][j & 3]
                                        + bp[j >> 2][j & 3]);
        }
    }

    f32x4 acc2[2][12];
    #pragma unroll
    for (int m = 0; m < 2; m++)
        #pragma unroll
        for (int nt = 0; nt < 12; nt++) acc2[m][nt] = (f32x4){0.f, 0.f, 0.f, 0.f};

    __syncthreads();                        // chunk-0 weights resident

    for (int c = 0; c < 12; c++) {
        f32x4 hacc[2][4];
        #pragma unroll
        for (int m = 0; m < 2; m++)
            #pragma unroll
            for (int nt = 0; nt < 4; nt++) hacc[m][nt] = (f32x4){0.f, 0.f, 0.f, 0.f};
        #pragma unroll
        for (int kk = 0; kk < 6; kk++) {
            int p = kk >> 1;
            int cc = (kk & 1) * 4 + quad;
            #pragma unroll
            for (int nt = 0; nt < 4; nt++) {
                int n = nt * 16 + l15;
                bf16x8 bfr = *(const bf16x8*)(&W1s[p * 4096 + n * 64 + ((cc ^ (n & 7)) << 3)]);
                #pragma unroll
                for (int m = 0; m < 2; m++)
                    hacc[m][nt] = __builtin_amdgcn_mfma_f32_16x16x32_bf16(af[m][kk], bfr, hacc[m][nt], 0, 0, 0);
            }
        }
        float b1v[4];
        #pragma unroll
        for (int nt = 0; nt < 4; nt++) b1v[nt] = b1[c * 64 + nt * 16 + l15];
        #pragma unroll
        for (int m = 0; m < 2; m++) {
            #pragma unroll
            for (int nt = 0; nt < 4; nt++) {
                #pragma unroll
                for (int r = 0; r < 4; r++) {
                    int i = wv * 32 + m * 16 + quad * 4 + r;
                    int hcol = nt * 16 + l15;
                    float a = hacc[m][nt][r] + b1v[nt];
                    float yv = 0.7978845608028654f * (a + 0.044715f * a * a * a);
                    float th = 1.0f - 2.0f / (__expf(2.0f * yv) + 1.0f);  // tanh(yv)
                    float gl = 0.5f * a * (1.0f + th);
                    Hs[i * 64 + (((hcol >> 3) ^ (i & 7)) << 3) + (hcol & 7)] = f2u(gl);
                }
            }
        }
        __syncthreads();                    // B1: Hs ready, W1s free, drains W2(c)

        if (c + 1 < 12) stageW1(c + 1);     // hides under gemm2

        #pragma unroll
        for (int kt = 0; kt < 2; kt++) {
            int cc = kt * 4 + quad;
            bf16x8 pa[2];
            #pragma unroll
            for (int m = 0; m < 2; m++) {
                int row = wv * 32 + m * 16 + l15;
                pa[m] = *(const bf16x8*)(&Hs[row * 64 + ((cc ^ (row & 7)) << 3)]);
            }
            #pragma unroll
            for (int nt = 0; nt < 12; nt++) {
                int n = nt * 16 + l15;
                bf16x8 wb = *(const bf16x8*)(&W2s[n * 64 + ((cc ^ (n & 7)) << 3)]);
                #pragma unroll
                for (int m = 0; m < 2; m++)
                    acc2[m][nt] = __builtin_amdgcn_mfma_f32_16x16x32_bf16(pa[m], wb, acc2[m][nt], 0, 0, 0);
            }
        }
        __syncthreads();                    // B2: W2s+Hs free, drains W1(c+1)

        if (c + 1 < 12) stageW2(c + 1);     // drained at next B1
    }

    #pragma unroll
    for (int nt = 0; nt < 12; nt++) {
        float bb = b2[nt * 16 + l15];
        #pragma unroll
        for (int m = 0; m < 2; m++) {
            #pragma unroll
            for (int r = 0; r < 4; r++) {
                int row = t0 + wv * 32 + m * 16 + quad * 4 + r;
                int col = nt * 16 + l15;
                size_t o = (size_t)row * CDIM + col;
                out[o] = acc2[m][nt][r] + bb + toF(X[o]);
            }
        }
    }
}

// ================= MFMA window attention =================
__global__ __launch_bounds__(256) void attn_kernel(const bf16* __restrict__ qkv,
                                                   const float* __restrict__ pos_emb,
                                                   bf16* __restrict__ y) {
    __shared__ ushort_t Ps[4][64 * 72];
    __shared__ ushort_t Vt[4][32 * 72];
    __shared__ float pe[169];

    int tid = threadIdx.x;
    int wv = tid >> 6, lane = tid & 63;
    int l15 = lane & 15, quad = lane >> 4;

    int per = gridDim.x >> 3;
    int sid = blockIdx.x;
    int bid = (sid & 7) * per + (sid >> 3);
    int gid = bid * 4 + wv;
    int h = gid % HEADS;
    int rest = gid / HEADS;
    int win = rest % NWIN;
    int b = rest / NWIN;
    int wi = win >> 4, wj = win & 15;

    for (int i = lane; i < 169; i += 64) pe[i] = pos_emb[i];
    __syncthreads();

    auto tok = [&](int i) -> int {
        i = min(i, 48);
        int pi = (i * 37) >> 8;
        int pj = i - pi * 7;
        int ui = wi * WS + pi + 3; if (ui >= HH) ui -= HH;
        int uj = wj * WS + pj + 3; if (uj >= WW) uj -= WW;
        return (b * HH + ui) * WW + uj;
    };

    bf16x8 qf[4], kf[4];
    #pragma unroll
    for (int t = 0; t < 4; t++) {
        size_t base = (size_t)tok(t * 16 + l15) * QKVW + h * HD + quad * 8;
        qf[t] = *(const bf16x8*)(qkv + base);
        kf[t] = *(const bf16x8*)(qkv + base + CDIM);
    }

    #pragma unroll
    for (int it = 0; it < 4; it++) {
        int idx = lane + it * 64;
        int p = idx >> 2, dc = idx & 3;
        size_t base = (size_t)tok(p) * QKVW + 2 * CDIM + h * HD + dc * 8;
        ushortx8 v = *(const ushortx8*)((const ushort_t*)qkv + base);
        #pragma unroll
        for (int jj = 0; jj < 8; jj++)
            Vt[wv][(dc * 8 + jj) * 72 + p] = v[jj];
    }

    f32x4 acc[4][4];
    #pragma unroll
    for (int mt = 0; mt < 4; mt++)
        #pragma unroll
        for (int nt = 0; nt < 4; nt++)
            acc[mt][nt] = (f32x4){0.f, 0.f, 0.f, 0.f};
    #pragma unroll
    for (int mt = 0; mt < 4; mt++)
        #pragma unroll
        for (int nt = 0; nt < 4; nt++)
            acc[mt][nt] = __builtin_amdgcn_mfma_f32_16x16x32_bf16(qf[mt], kf[nt], acc[mt][nt], 0, 0, 0);

    bool m_ul = (wi == NWH - 1);
    bool m_lr = (wj == NWW - 1);
    int kpi[4], kpj[4];
    bool jval[4];
    #pragma unroll
    for (int nt = 0; nt < 4; nt++) {
        int j = nt * 16 + l15;
        jval[nt] = (j < WS2);
        int jc = min(j, 48);
        kpi[nt] = (jc * 37) >> 8;
        kpj[nt] = jc - kpi[nt] * 7;
    }
    #pragma unroll
    for (int mt = 0; mt < 4; mt++) {
        #pragma unroll
        for (int r = 0; r < 4; r++) {
            int i = mt * 16 + quad * 4 + r;
            int ic = min(i, 48);
            int pi = (ic * 37) >> 8;
            int pj = ic - pi * 7;
            #pragma unroll
            for (int nt = 0; nt < 4; nt++) {
                float s = acc[mt][nt][r] * 0.17677669529663689f
                        + pe[(pi - kpi[nt] + 6) * 13 + (pj - kpj[nt] + 6)];
                if (m_ul && ((pi >= 4) != (kpi[nt] >= 4))) s += NEGV;
                if (m_lr && ((pj >= 4) != (kpj[nt] >= 4))) s += NEGV;
                if (!jval[nt]) s = NEGV;
                acc[mt][nt][r] = s;
            }
            float mx = fmaxf(fmaxf(acc[mt][0][r], acc[mt][1][r]),
                             fmaxf(acc[mt][2][r], acc[mt][3][r]));
            #pragma unroll
            for (int o = 1; o < 16; o <<= 1) mx = fmaxf(mx, __shfl_xor(mx, o, 64));
            float sum = 0.f;
            #pragma unroll
            for (int nt = 0; nt < 4; nt++) {
                float e = __expf(acc[mt][nt][r] - mx);
                acc[mt][nt][r] = e;
                sum += e;
            }
            #pragma unroll
            for (int o = 1; o < 16; o <<= 1) sum += __shfl_xor(sum, o, 64);
            float inv = 1.0f / sum;
            #pragma unroll
            for (int nt = 0; nt < 4; nt++) acc[mt][nt][r] *= inv;
        }
    }

    #pragma unroll
    for (int mt = 0; mt < 4; mt++)
        #pragma unroll
        for (int nt = 0; nt < 4; nt++)
            #pragma unroll
            for (int r = 0; r < 4; r++)
                Ps[wv][(mt * 16 + quad * 4 + r) * 72 + nt * 16 + l15] = f2u(acc[mt][nt][r]);

    f32x4 oacc[4][2];
    #pragma unroll
    for (int mt = 0; mt < 4; mt++)
        #pragma unroll
        for (int nt = 0; nt < 2; nt++)
            oacc[mt][nt] = (f32x4){0.f, 0.f, 0.f, 0.f};
    #pragma unroll
    for (int kt = 0; kt < 2; kt++) {
        bf16x8 pa[4], vb[2];
        #pragma unroll
        for (int mt = 0; mt < 4; mt++)
            pa[mt] = *(const bf16x8*)(&Ps[wv][(mt * 16 + l15) * 72 + kt * 32 + quad * 8]);
        #pragma unroll
        for (int nt = 0; nt < 2; nt++)
            vb[nt] = *(const bf16x8*)(&Vt[wv][(nt * 16 + l15) * 72 + kt * 32 + quad * 8]);
        #pragma unroll
        for (int mt = 0; mt < 4; mt++)
            #pragma unroll
            for (int nt = 0; nt < 2; nt++)
                oacc[mt][nt] = __builtin_amdgcn_mfma_f32_16x16x32_bf16(pa[mt], vb[nt], oacc[mt][nt], 0, 0, 0);
    }

    #pragma unroll
    for (int mt = 0; mt < 4; mt++) {
        #pragma unroll
        for (int r = 0; r < 4; r++) {
            int i = mt * 16 + quad * 4 + r;
            if (i < WS2) {
                size_t base = (size_t)tok(i) * CDIM + h * HD + l15;
                #pragma unroll
                for (int nt = 0; nt < 2; nt++)
                    y[base + nt * 16] = f2b(oacc[mt][nt][r]);
            }
        }
    }
}

extern "C" void kernel_launch(void* const* d_in, const int* in_sizes, int n_in,
                              void* d_out, int out_size, void* d_ws, size_t ws_size,
                              hipStream_t stream) {
    float* out = (float*)d_out;   // reference output dtype: float32

    size_t szA = (size_t)NTOK * CDIM * sizeof(bf16);   // (bufA slot retained; unused)
    size_t szQ = (size_t)NTOK * QKVW * sizeof(bf16);
    size_t szY = (size_t)NTOK * CDIM * sizeof(bf16);
    size_t szX = (size_t)NTOK * CDIM * sizeof(bf16);
    size_t szP = 3072 * sizeof(float);
    size_t szT = 442368 * sizeof(ushort_t);
    if (ws_size < szA + szQ + szY + szX + szP + szT) return;
    bf16*     bufQ = (bf16*)((char*)d_ws + szA);
    bf16*     bufY = (bf16*)((char*)d_ws + szA + szQ);
    bf16*     bufX = (bf16*)((char*)d_ws + szA + szQ + szY);
    float*    cW   = (float*)((char*)d_ws + szA + szQ + szY + szX);
    ushort_t* cT   = (ushort_t*)((char*)d_ws + szA + szQ + szY + szX + szP);

    float* cBout = cW + 0;      // 192
    float* cPe   = cW + 192;    // 169
    float* cL1g  = cW + 384;
    float* cL1b  = cW + 576;
    float* cL2g  = cW + 768;
    float* cL2b  = cW + 960;
    float* cB1   = cW + 1152;   // 768
    float* cB2   = cW + 1920;   // 192

    ushort_t* tWqkv = cT + 0;        // [576][192]
    ushort_t* tWout = cT + 110592;   // [192][192]
    ushort_t* tW1   = cT + 147456;   // [768][192]
    ushort_t* tW2   = cT + 294912;   // [192][768]

    dim3 b256(256);
    canon_small_kernel<<<9, b256, 0, stream>>>(
        d_in[3], d_in[4], d_in[5], d_in[6], d_in[7], d_in[8], d_in[10], d_in[12], cW);
    canon_bt4_kernel<<<1728, b256, 0, stream>>>(
        d_in[1], d_in[2], d_in[9], d_in[11], cT);

    int gM  = NTOK / 128;               // 784
    int gAT = BATCH * NWIN * HEADS / 4; // 3072 blocks, 4 window-heads each
    int gF  = NTOK / 128;               // 784

    // qkv = LN1(x) @ Wqkv  (LN1 fused, reg-A)
    gemm192f_kernel<0, 9><<<gM * 9, b256, 0, stream>>>(
        d_in[0], tWqkv, QKVW, cL1g, cL1b, nullptr, nullptr, bufQ);
    attn_kernel<<<gAT, b256, 0, stream>>>(bufQ, cPe, bufY);
    // x1 = attn_out @ Wout + b + x  (reg-A)
    gemm192f_kernel<1, 3><<<gM * 3, b256, 0, stream>>>(
        bufY, tWout, CDIM, nullptr, nullptr, cBout, d_in[0], bufX);
    fused_mlp_kernel<<<gF, b256, 0, stream>>>(
        bufX, tW1, tW2, cL2g, cL2b, cB1, cB2, out);
}

// Round 9
// 510.526 us; speedup vs baseline: 1.0310x; 1.0310x over previous
//
#include <hip/hip_runtime.h>
#include <hip/hip_bf16.h>
#include <math.h>

typedef __hip_bfloat16 bf16;
typedef unsigned short ushort_t;
typedef __bf16 bf16x8 __attribute__((ext_vector_type(8)));
typedef unsigned short ushortx8 __attribute__((ext_vector_type(8)));
typedef float  f32x4  __attribute__((ext_vector_type(4)));

#define BATCH 8
#define HH 112
#define WW 112
#define CDIM 192
#define HEADS 6
#define HD 32
#define QKVW 576
#define MLPW 768
#define WS 7
#define WS2 49
#define NWH 16
#define NWW 16
#define NWIN 256
#define NTOK (BATCH*HH*WW)   // 100352
#define NEGV (-1e9f)

typedef __attribute__((address_space(3))) void lds_void;
typedef const __attribute__((address_space(1))) void gbl_void;

__device__ __forceinline__ float toF(float v) { return v; }
__device__ __forceinline__ float toF(bf16 v) { return __bfloat162float(v); }
__device__ __forceinline__ bf16  f2b(float v) { return __float2bfloat16(v); }
__device__ __forceinline__ ushort_t f2u(float v) { bf16 b = __float2bfloat16(v); return *(ushort_t*)&b; }

// Per-array dtype probe (first 16 words). Deterministic.
__device__ __forceinline__ bool probe_is_bf16(const void* p) {
    const unsigned int* w = (const unsigned int*)p;
    int nz = 0, band = 0;
    #pragma unroll
    for (int i = 0; i < 16; i++) {
        unsigned int v = w[i];
        if (v == 0u) continue;
        nz++;
        unsigned int lo = v & 0xFFFFu, hi = v >> 16;
        unsigned int elo = (lo >> 7) & 0xFFu, ehi = (hi >> 7) & 0xFFu;
        bool okl = (lo != 0u) && (elo >= 0x60u) && (elo <= 0x9Fu);
        bool okh = (hi != 0u) && (ehi >= 0x60u) && (ehi <= 0x9Fu);
        if (okl && okh) band++;
    }
    return (nz == 0) || (band == nz);
}

__device__ __forceinline__ float read_any(const void* p, size_t i, bool isb) {
    return isb ? toF(((const bf16*)p)[i]) : ((const float*)p)[i];
}

__device__ __forceinline__ float wave_sum(float v) {
    #pragma unroll
    for (int o = 1; o < 64; o <<= 1) v += __shfl_xor(v, o, 64);
    return v;
}

// ---------------- Fused canon of all 8 small fp32 params (1 launch) ----------------
__global__ void canon_small_kernel(const void* s0, const void* s1, const void* s2,
                                   const void* s3, const void* s4, const void* s5,
                                   const void* s6, const void* s7,
                                   float* __restrict__ cW) {
    const void* srcs[8] = {s0, s1, s2, s3, s4, s5, s6, s7};
    const int off[8]  = {0, 192, 361, 553, 745, 937, 1129, 1897};
    const int cnt[8]  = {192, 169, 192, 192, 192, 192, 768, 192};
    const int doff[8] = {0, 192, 384, 576, 768, 960, 1152, 1920};
    int i = blockIdx.x * 256 + threadIdx.x;
    if (i >= 2089) return;
    int s = 0;
    #pragma unroll
    for (int k = 1; k < 8; k++) if (i >= off[k]) s = k;
    int j = i - off[s];
    if (j < cnt[s]) {
        bool isb = probe_is_bf16(srcs[s]);
        cW[doff[s] + j] = read_any(srcs[s], j, isb);
    }
}

// ---------------- Fused canon+transpose of all 4 weights (1 launch) ----------------
__global__ void canon_bt4_kernel(const void* w0, const void* w1, const void* w2,
                                 const void* w3, ushort_t* __restrict__ cT) {
    int bid = blockIdx.x;
    const void* src; ushort_t* dst; int K, N, base;
    if (bid < 432)       { src = w0; dst = cT;          K = CDIM; N = QKVW; base = bid; }
    else if (bid < 576)  { src = w1; dst = cT + 110592; K = CDIM; N = CDIM; base = bid - 432; }
    else if (bid < 1152) { src = w2; dst = cT + 147456; K = CDIM; N = MLPW; base = bid - 576; }
    else                 { src = w3; dst = cT + 294912; K = MLPW; N = CDIM; base = bid - 1152; }
    int i = base * 256 + threadIdx.x;
    if (i < K * N) {
        bool isb = probe_is_bf16(src);
        int k = i / N, n = i % N;
        dst[(size_t)n * K + k] = f2u(read_any(src, i, isb));
    }
}

// ---------------- LN1: raw x (probed) -> bf16 ----------------
__global__ void ln1_kernel(const void* __restrict__ xraw, const float* __restrict__ g,
                           const float* __restrict__ bta, bf16* __restrict__ out) {
    bool xb = probe_is_bf16(xraw);
    int wave = threadIdx.x >> 6, lane = threadIdx.x & 63;
    int t = blockIdx.x * 4 + wave;
    size_t base = (size_t)t * CDIM;
    float v[3];
    #pragma unroll
    for (int i = 0; i < 3; i++) v[i] = read_any(xraw, base + lane + 64 * i, xb);
    float s  = v[0] + v[1] + v[2];
    float s2 = v[0]*v[0] + v[1]*v[1] + v[2]*v[2];
    s = wave_sum(s); s2 = wave_sum(s2);
    float mu = s * (1.0f / CDIM);
    float var = s2 * (1.0f / CDIM) - mu * mu;
    float rs = rsqrtf(var + 1e-5f);
    #pragma unroll
    for (int i = 0; i < 3; i++) {
        int c = lane + 64 * i;
        out[base + c] = f2b((v[i] - mu) * rs * g[c] + bta[c]);
    }
}

// ========== Reg-A MFMA GEMM for K=192 (A = bf16 token-major, no A-LDS) ==========
// A is token-major [tok][192]: the MFMA A-fragment [l15=row][quad*8+j=k] loads
// DIRECTLY from global as one bf16x8/lane (16 fully-used cache lines per
// wave-load). Only B (weight) is staged: 24 KB via global_load_lds w16 +
// both-sides XOR swizzle, issued FIRST so its latency hides under the A loads.
// ONE barrier. Wave owns 32 rows (2 M-tiles): each B-frag read feeds 2 MFMAs.
// LDS 24 KB (was 72) -> occupancy VGPR-bound (~4 blocks/CU vs 2).
// Round-7 lesson: NO LN fusion here (9x recompute + fp32 reads regressed);
// LN1 stays a separate kernel producing bf16 bufA.
// EPI 0: plain bf16 store (qkv). EPI 1: +bias +probed-x residual -> bf16 (proj).
template <int EPI, int NY>
__global__ __launch_bounds__(256) void gemm192r_kernel(
    const ushort_t* __restrict__ A,  // bf16 [NTOK][192]
    const ushort_t* __restrict__ BT, // bf16 [N][192]
    const int N,
    const float* __restrict__ bias,
    const void* __restrict__ res,
    void* __restrict__ out)
{
    __shared__ ushort_t Bs[3][64 * 64];
    int tid = threadIdx.x;
    int per = gridDim.x >> 3;
    int sid = blockIdx.x;
    int w = (sid & 7) * per + (sid >> 3);
    int t0 = (w / NY) * 128;
    int n0 = (w % NY) * 64;
    int lane = tid & 63, wv = tid >> 6;
    int l15 = lane & 15, quad = lane >> 4;
    int lr = lane >> 3, lc = lane & 7;

    // ---- stage B first (3 panels [64][64], 6 instr/thread) ----
    #pragma unroll
    for (int p = 0; p < 3; p++) {
        #pragma unroll
        for (int it = 0; it < 2; it++) {
            int r = wv * 16 + it * 8 + lr;                 // r&7 == lr
            const ushort_t* src = &BT[(size_t)(n0 + r) * 192 + p * 64 + ((lc ^ lr) << 3)];
            __builtin_amdgcn_global_load_lds(
                (gbl_void*)src, (lds_void*)&Bs[p][(wv * 16 + it * 8) * 64], 16, 0, 0);
        }
    }

    // ---- A fragments straight from global (hides B-stage latency) ----
    bf16x8 af[2][6];
    #pragma unroll
    for (int m = 0; m < 2; m++) {
        size_t rb = (size_t)(t0 + wv * 32 + m * 16 + l15) * CDIM;
        #pragma unroll
        for (int kk = 0; kk < 6; kk++)
            af[m][kk] = *(const bf16x8*)(A + rb + kk * 32 + quad * 8);
    }

    f32x4 acc[2][4];
    #pragma unroll
    for (int i = 0; i < 2; i++)
        #pragma unroll
        for (int j = 0; j < 4; j++)
            acc[i][j] = (f32x4){0.f, 0.f, 0.f, 0.f};

    __syncthreads();    // Bs resident

    #pragma unroll
    for (int kk = 0; kk < 6; kk++) {
        int p = kk >> 1;
        int cs = ((((kk & 1) * 4 + quad)) ^ (l15 & 7)) << 3;
        bf16x8 bfr[4];
        #pragma unroll
        for (int j = 0; j < 4; j++)
            bfr[j] = *(const bf16x8*)(&Bs[p][(j * 16 + l15) * 64 + cs]);
        #pragma unroll
        for (int i = 0; i < 2; i++)
            #pragma unroll
            for (int j = 0; j < 4; j++)
                acc[i][j] = __builtin_amdgcn_mfma_f32_16x16x32_bf16(af[i][kk], bfr[j], acc[i][j], 0, 0, 0);
    }

    bool xb = false;
    if (EPI == 1) xb = probe_is_bf16(res);

    #pragma unroll
    for (int i = 0; i < 2; i++) {
        #pragma unroll
        for (int j = 0; j < 4; j++) {
            #pragma unroll
            for (int r = 0; r < 4; r++) {
                int row = wv * 32 + i * 16 + quad * 4 + r;
                int col = n0 + j * 16 + l15;
                size_t t = (size_t)(t0 + row);
                float v = acc[i][j][r];
                if (EPI == 0) {
                    ((bf16*)out)[t * N + col] = f2b(v);
                } else {
                    size_t o = t * CDIM + col;
                    ((bf16*)out)[o] = f2b(v + bias[col] + read_any(res, o, xb));
                }
            }
        }
    }
}

// ================= Fused LN2 + MLP1(+GELU) + MLP2 (+residual), v5 =================
// Round-4 structure (measured ~155us, VGPR 128, no spill): block = 256 thr
// = 4 waves = 128 tokens, wave owns 32 rows (2 M-tiles), LDS 64 KB, 2 blocks/CU.
// __launch_bounds__(256,2): VGPR cap 256 — fat-wave working set needs ~200.
__global__ __launch_bounds__(256, 2) void fused_mlp_kernel(
    const bf16* __restrict__ X,        // [NTOK][192] bf16 (pre-LN residual = x1)
    const ushort_t* __restrict__ W1T,  // [768][192]
    const ushort_t* __restrict__ W2T,  // [192][768]
    const float* __restrict__ g, const float* __restrict__ bta,
    const float* __restrict__ b1, const float* __restrict__ b2,
    float* __restrict__ out)
{
    __shared__ ushort_t W1s[3 * 64 * 64];   // (24 KB)
    __shared__ ushort_t W2s[192 * 64];      // (24 KB)
    __shared__ ushort_t Hs[128 * 64];       // (16 KB)
    int tid = threadIdx.x;
    int lane = tid & 63, wv = tid >> 6;     // wv 0..3
    int l15 = lane & 15, quad = lane >> 4;
    int lr = lane >> 3, lc = lane & 7;
    int t0 = blockIdx.x * 128;

    auto stageW1 = [&](int c) {
        #pragma unroll
        for (int p = 0; p < 3; p++)
            #pragma unroll
            for (int rg = 0; rg < 2; rg++) {
                int rowb = wv * 16 + rg * 8;
                const ushort_t* src =
                    &W1T[(size_t)(c * 64 + rowb + lr) * CDIM + p * 64 + ((lc ^ lr) << 3)];
                __builtin_amdgcn_global_load_lds(
                    (gbl_void*)src, (lds_void*)&W1s[p * 4096 + rowb * 64], 16, 0, 0);
            }
    };
    auto stageW2 = [&](int c) {
        #pragma unroll
        for (int rg = 0; rg < 6; rg++) {
            int rowb = wv * 48 + rg * 8;
            const ushort_t* src =
                &W2T[(size_t)(rowb + lr) * MLPW + c * 64 + ((lc ^ lr) << 3)];
            __builtin_amdgcn_global_load_lds(
                (gbl_void*)src, (lds_void*)&W2s[rowb * 64], 16, 0, 0);
        }
    };

    stageW1(0);
    stageW2(0);

    // ---- LN2 into register A-fragments, in place (wave's 2 x 16 rows) ----
    bf16x8 af[2][6];
    float s[2] = {0.f, 0.f}, s2[2] = {0.f, 0.f};
    #pragma unroll
    for (int m = 0; m < 2; m++) {
        size_t rb = (size_t)(t0 + wv * 32 + m * 16 + l15) * CDIM;
        #pragma unroll
        for (int kk = 0; kk < 6; kk++) {
            af[m][kk] = *(const bf16x8*)((const ushort_t*)X + rb + kk * 32 + quad * 8);
            #pragma unroll
            for (int j = 0; j < 8; j++) {
                float f = (float)af[m][kk][j];
                s[m] += f; s2[m] += f * f;
            }
        }
    }
    #pragma unroll
    for (int m = 0; m < 2; m++) {
        s[m]  += __shfl_xor(s[m], 16, 64);  s[m]  += __shfl_xor(s[m], 32, 64);
        s2[m] += __shfl_xor(s2[m], 16, 64); s2[m] += __shfl_xor(s2[m], 32, 64);
    }
    #pragma unroll
    for (int kk = 0; kk < 6; kk++) {
        int c0 = kk * 32 + quad * 8;
        float4 g0 = *(const float4*)(g + c0), g1 = *(const float4*)(g + c0 + 4);
        float4 b0 = *(const float4*)(bta + c0), b1v = *(const float4*)(bta + c0 + 4);
        const float* gp[2] = {&g0.x, &g1.x};
        const float* bp[2] = {&b0.x, &b1v.x};
        #pragma unroll
        for (int m = 0; m < 2; m++) {
            float mu = s[m] * (1.0f / CDIM);
            float var = s2[m] * (1.0f / CDIM) - mu * mu;
            float rs = rsqrtf(var + 1e-5f);
            #pragma unroll
            for (int j = 0; j < 8; j++)
                af[m][kk][j] = (__bf16)(((float)af[m][kk][j] - mu) * rs * gp[j >> 2][j & 3]
                                        + bp[j >> 2][j & 3]);
        }
    }

    f32x4 acc2[2][12];
    #pragma unroll
    for (int m = 0; m < 2; m++)
        #pragma unroll
        for (int nt = 0; nt < 12; nt++) acc2[m][nt] = (f32x4){0.f, 0.f, 0.f, 0.f};

    __syncthreads();                        // chunk-0 weights resident

    for (int c = 0; c < 12; c++) {
        f32x4 hacc[2][4];
        #pragma unroll
        for (int m = 0; m < 2; m++)
            #pragma unroll
            for (int nt = 0; nt < 4; nt++) hacc[m][nt] = (f32x4){0.f, 0.f, 0.f, 0.f};
        #pragma unroll
        for (int kk = 0; kk < 6; kk++) {
            int p = kk >> 1;
            int cc = (kk & 1) * 4 + quad;
            #pragma unroll
            for (int nt = 0; nt < 4; nt++) {
                int n = nt * 16 + l15;
                bf16x8 bfr = *(const bf16x8*)(&W1s[p * 4096 + n * 64 + ((cc ^ (n & 7)) << 3)]);
                #pragma unroll
                for (int m = 0; m < 2; m++)
                    hacc[m][nt] = __builtin_amdgcn_mfma_f32_16x16x32_bf16(af[m][kk], bfr, hacc[m][nt], 0, 0, 0);
            }
        }
        float b1v[4];
        #pragma unroll
        for (int nt = 0; nt < 4; nt++) b1v[nt] = b1[c * 64 + nt * 16 + l15];
        #pragma unroll
        for (int m = 0; m < 2; m++) {
            #pragma unroll
            for (int nt = 0; nt < 4; nt++) {
                #pragma unroll
                for (int r = 0; r < 4; r++) {
                    int i = wv * 32 + m * 16 + quad * 4 + r;
                    int hcol = nt * 16 + l15;
                    float a = hacc[m][nt][r] + b1v[nt];
                    float yv = 0.7978845608028654f * (a + 0.044715f * a * a * a);
                    float th = 1.0f - 2.0f / (__expf(2.0f * yv) + 1.0f);  // tanh(yv)
                    float gl = 0.5f * a * (1.0f + th);
                    Hs[i * 64 + (((hcol >> 3) ^ (i & 7)) << 3) + (hcol & 7)] = f2u(gl);
                }
            }
        }
        __syncthreads();                    // B1: Hs ready, W1s free, drains W2(c)

        if (c + 1 < 12) stageW1(c + 1);     // hides under gemm2

        #pragma unroll
        for (int kt = 0; kt < 2; kt++) {
            int cc = kt * 4 + quad;
            bf16x8 pa[2];
            #pragma unroll
            for (int m = 0; m < 2; m++) {
                int row = wv * 32 + m * 16 + l15;
                pa[m] = *(const bf16x8*)(&Hs[row * 64 + ((cc ^ (row & 7)) << 3)]);
            }
            #pragma unroll
            for (int nt = 0; nt < 12; nt++) {
                int n = nt * 16 + l15;
                bf16x8 wb = *(const bf16x8*)(&W2s[n * 64 + ((cc ^ (n & 7)) << 3)]);
                #pragma unroll
                for (int m = 0; m < 2; m++)
                    acc2[m][nt] = __builtin_amdgcn_mfma_f32_16x16x32_bf16(pa[m], wb, acc2[m][nt], 0, 0, 0);
            }
        }
        __syncthreads();                    // B2: W2s+Hs free, drains W1(c+1)

        if (c + 1 < 12) stageW2(c + 1);     // drained at next B1
    }

    #pragma unroll
    for (int nt = 0; nt < 12; nt++) {
        float bb = b2[nt * 16 + l15];
        #pragma unroll
        for (int m = 0; m < 2; m++) {
            #pragma unroll
            for (int r = 0; r < 4; r++) {
                int row = t0 + wv * 32 + m * 16 + quad * 4 + r;
                int col = nt * 16 + l15;
                size_t o = (size_t)row * CDIM + col;
                out[o] = acc2[m][nt][r] + bb + toF(X[o]);
            }
        }
    }
}

// ================= MFMA window attention =================
// 1 wave = 1 (batch, window, head). Swapped PV: since A- and B-fragments share
// the [l15][quad*8+j] shape, mfma(vb, pa) yields O^T (row=d=quad*4+r, col=i=l15)
// -> 4 consecutive d per thread -> 8B packed stores (8 instead of 32 scalar).
__global__ __launch_bounds__(256) void attn_kernel(const bf16* __restrict__ qkv,
                                                   const float* __restrict__ pos_emb,
                                                   bf16* __restrict__ y) {
    __shared__ ushort_t Ps[4][64 * 72];
    __shared__ ushort_t Vt[4][32 * 72];
    __shared__ float pe[169];

    int tid = threadIdx.x;
    int wv = tid >> 6, lane = tid & 63;
    int l15 = lane & 15, quad = lane >> 4;

    int per = gridDim.x >> 3;
    int sid = blockIdx.x;
    int bid = (sid & 7) * per + (sid >> 3);
    int gid = bid * 4 + wv;
    int h = gid % HEADS;
    int rest = gid / HEADS;
    int win = rest % NWIN;
    int b = rest / NWIN;
    int wi = win >> 4, wj = win & 15;

    for (int i = lane; i < 169; i += 64) pe[i] = pos_emb[i];
    __syncthreads();

    auto tok = [&](int i) -> int {
        i = min(i, 48);
        int pi = (i * 37) >> 8;
        int pj = i - pi * 7;
        int ui = wi * WS + pi + 3; if (ui >= HH) ui -= HH;
        int uj = wj * WS + pj + 3; if (uj >= WW) uj -= WW;
        return (b * HH + ui) * WW + uj;
    };

    bf16x8 qf[4], kf[4];
    #pragma unroll
    for (int t = 0; t < 4; t++) {
        size_t base = (size_t)tok(t * 16 + l15) * QKVW + h * HD + quad * 8;
        qf[t] = *(const bf16x8*)(qkv + base);
        kf[t] = *(const bf16x8*)(qkv + base + CDIM);
    }

    #pragma unroll
    for (int it = 0; it < 4; it++) {
        int idx = lane + it * 64;
        int p = idx >> 2, dc = idx & 3;
        size_t base = (size_t)tok(p) * QKVW + 2 * CDIM + h * HD + dc * 8;
        ushortx8 v = *(const ushortx8*)((const ushort_t*)qkv + base);
        #pragma unroll
        for (int jj = 0; jj < 8; jj++)
            Vt[wv][(dc * 8 + jj) * 72 + p] = v[jj];
    }

    f32x4 acc[4][4];
    #pragma unroll
    for (int mt = 0; mt < 4; mt++)
        #pragma unroll
        for (int nt = 0; nt < 4; nt++)
            acc[mt][nt] = (f32x4){0.f, 0.f, 0.f, 0.f};
    #pragma unroll
    for (int mt = 0; mt < 4; mt++)
        #pragma unroll
        for (int nt = 0; nt < 4; nt++)
            acc[mt][nt] = __builtin_amdgcn_mfma_f32_16x16x32_bf16(qf[mt], kf[nt], acc[mt][nt], 0, 0, 0);

    bool m_ul = (wi == NWH - 1);
    bool m_lr = (wj == NWW - 1);
    int kpi[4], kpj[4];
    bool jval[4];
    #pragma unroll
    for (int nt = 0; nt < 4; nt++) {
        int j = nt * 16 + l15;
        jval[nt] = (j < WS2);
        int jc = min(j, 48);
        kpi[nt] = (jc * 37) >> 8;
        kpj[nt] = jc - kpi[nt] * 7;
    }
    #pragma unroll
    for (int mt = 0; mt < 4; mt++) {
        #pragma unroll
        for (int r = 0; r < 4; r++) {
            int i = mt * 16 + quad * 4 + r;
            int ic = min(i, 48);
            int pi = (ic * 37) >> 8;
            int pj = ic - pi * 7;
            #pragma unroll
            for (int nt = 0; nt < 4; nt++) {
                float s = acc[mt][nt][r] * 0.17677669529663689f
                        + pe[(pi - kpi[nt] + 6) * 13 + (pj - kpj[nt] + 6)];
                if (m_ul && ((pi >= 4) != (kpi[nt] >= 4))) s += NEGV;
                if (m_lr && ((pj >= 4) != (kpj[nt] >= 4))) s += NEGV;
                if (!jval[nt]) s = NEGV;
                acc[mt][nt][r] = s;
            }
            float mx = fmaxf(fmaxf(acc[mt][0][r], acc[mt][1][r]),
                             fmaxf(acc[mt][2][r], acc[mt][3][r]));
            #pragma unroll
            for (int o = 1; o < 16; o <<= 1) mx = fmaxf(mx, __shfl_xor(mx, o, 64));
            float sum = 0.f;
            #pragma unroll
            for (int nt = 0; nt < 4; nt++) {
                float e = __expf(acc[mt][nt][r] - mx);
                acc[mt][nt][r] = e;
                sum += e;
            }
            #pragma unroll
            for (int o = 1; o < 16; o <<= 1) sum += __shfl_xor(sum, o, 64);
            float inv = 1.0f / sum;
            #pragma unroll
            for (int nt = 0; nt < 4; nt++) acc[mt][nt][r] *= inv;
        }
    }

    #pragma unroll
    for (int mt = 0; mt < 4; mt++)
        #pragma unroll
        for (int nt = 0; nt < 4; nt++)
            #pragma unroll
            for (int r = 0; r < 4; r++)
                Ps[wv][(mt * 16 + quad * 4 + r) * 72 + nt * 16 + l15] = f2u(acc[mt][nt][r]);

    // ---- O^T = mfma(Vt-frag, Ps-frag): row=d (dt tiles), col=i (it tiles) ----
    f32x4 oaccT[2][4];
    #pragma unroll
    for (int dt = 0; dt < 2; dt++)
        #pragma unroll
        for (int it = 0; it < 4; it++)
            oaccT[dt][it] = (f32x4){0.f, 0.f, 0.f, 0.f};
    #pragma unroll
    for (int kt = 0; kt < 2; kt++) {
        bf16x8 pa[4], vb[2];
        #pragma unroll
        for (int it = 0; it < 4; it++)
            pa[it] = *(const bf16x8*)(&Ps[wv][(it * 16 + l15) * 72 + kt * 32 + quad * 8]);
        #pragma unroll
        for (int dt = 0; dt < 2; dt++)
            vb[dt] = *(const bf16x8*)(&Vt[wv][(dt * 16 + l15) * 72 + kt * 32 + quad * 8]);
        #pragma unroll
        for (int dt = 0; dt < 2; dt++)
            #pragma unroll
            for (int it = 0; it < 4; it++)
                oaccT[dt][it] = __builtin_amdgcn_mfma_f32_16x16x32_bf16(vb[dt], pa[it], oaccT[dt][it], 0, 0, 0);
    }

    // ---- scatter O: per (it): token i = it*16+l15; 2 x 8B packed stores ----
    #pragma unroll
    for (int it = 0; it < 4; it++) {
        int i = it * 16 + l15;
        if (i < WS2) {
            size_t base = (size_t)tok(i) * CDIM + h * HD + quad * 4;
            #pragma unroll
            for (int dt = 0; dt < 2; dt++) {
                unsigned int u0 = (unsigned int)f2u(oaccT[dt][it][0])
                                | ((unsigned int)f2u(oaccT[dt][it][1]) << 16);
                unsigned int u1 = (unsigned int)f2u(oaccT[dt][it][2])
                                | ((unsigned int)f2u(oaccT[dt][it][3]) << 16);
                *(uint2*)((ushort_t*)y + base + dt * 16) = make_uint2(u0, u1);
            }
        }
    }
}

extern "C" void kernel_launch(void* const* d_in, const int* in_sizes, int n_in,
                              void* d_out, int out_size, void* d_ws, size_t ws_size,
                              hipStream_t stream) {
    float* out = (float*)d_out;   // reference output dtype: float32

    size_t szA = (size_t)NTOK * CDIM * sizeof(bf16);
    size_t szQ = (size_t)NTOK * QKVW * sizeof(bf16);
    size_t szY = (size_t)NTOK * CDIM * sizeof(bf16);
    size_t szX = (size_t)NTOK * CDIM * sizeof(bf16);
    size_t szP = 3072 * sizeof(float);
    size_t szT = 442368 * sizeof(ushort_t);
    if (ws_size < szA + szQ + szY + szX + szP + szT) return;
    bf16*     bufA = (bf16*)d_ws;
    bf16*     bufQ = (bf16*)((char*)d_ws + szA);
    bf16*     bufY = (bf16*)((char*)d_ws + szA + szQ);
    bf16*     bufX = (bf16*)((char*)d_ws + szA + szQ + szY);
    float*    cW   = (float*)((char*)d_ws + szA + szQ + szY + szX);
    ushort_t* cT   = (ushort_t*)((char*)d_ws + szA + szQ + szY + szX + szP);

    float* cBout = cW + 0;      // 192
    float* cPe   = cW + 192;    // 169
    float* cL1g  = cW + 384;
    float* cL1b  = cW + 576;
    float* cL2g  = cW + 768;
    float* cL2b  = cW + 960;
    float* cB1   = cW + 1152;   // 768
    float* cB2   = cW + 1920;   // 192

    ushort_t* tWqkv = cT + 0;        // [576][192]
    ushort_t* tWout = cT + 110592;   // [192][192]
    ushort_t* tW1   = cT + 147456;   // [768][192]
    ushort_t* tW2   = cT + 294912;   // [192][768]

    dim3 b256(256);
    canon_small_kernel<<<9, b256, 0, stream>>>(
        d_in[3], d_in[4], d_in[5], d_in[6], d_in[7], d_in[8], d_in[10], d_in[12], cW);
    canon_bt4_kernel<<<1728, b256, 0, stream>>>(
        d_in[1], d_in[2], d_in[9], d_in[11], cT);

    int gLN = NTOK / 4;                 // 25088
    int gM  = NTOK / 128;               // 784
    int gAT = BATCH * NWIN * HEADS / 4; // 3072 blocks, 4 window-heads each
    int gF  = NTOK / 128;               // 784

    ln1_kernel<<<gLN, b256, 0, stream>>>(d_in[0], cL1g, cL1b, bufA);
    gemm192r_kernel<0, 9><<<gM * 9, b256, 0, stream>>>(
        (const ushort_t*)bufA, tWqkv, QKVW, nullptr, nullptr, bufQ);
    attn_kernel<<<gAT, b256, 0, stream>>>(bufQ, cPe, bufY);
    gemm192r_kernel<1, 3><<<gM * 3, b256, 0, stream>>>(
        (const ushort_t*)bufY, tWout, CDIM, cBout, d_in[0], bufX);
    fused_mlp_kernel<<<gF, b256, 0, stream>>>(
        bufX, tW1, tW2, cL2g, cL2b, cB1, cB2, out);
}

// Round 10
// 486.576 us; speedup vs baseline: 1.0817x; 1.0492x over previous
//
#include <hip/hip_runtime.h>
#include <hip/hip_bf16.h>
#include <math.h>

typedef __hip_bfloat16 bf16;
typedef unsigned short ushort_t;
typedef __bf16 bf16x8 __attribute__((ext_vector_type(8)));
typedef unsigned short ushortx8 __attribute__((ext_vector_type(8)));
typedef float  f32x4  __attribute__((ext_vector_type(4)));

#define BATCH 8
#define HH 112
#define WW 112
#define CDIM 192
#define HEADS 6
#define HD 32
#define QKVW 576
#define MLPW 768
#define WS 7
#define WS2 49
#define NWH 16
#define NWW 16
#define NWIN 256
#define NTOK (BATCH*HH*WW)   // 100352
#define NEGV (-1e9f)

typedef __attribute__((address_space(3))) void lds_void;
typedef const __attribute__((address_space(1))) void gbl_void;

__device__ __forceinline__ float toF(float v) { return v; }
__device__ __forceinline__ float toF(bf16 v) { return __bfloat162float(v); }
__device__ __forceinline__ bf16  f2b(float v) { return __float2bfloat16(v); }
__device__ __forceinline__ ushort_t f2u(float v) { bf16 b = __float2bfloat16(v); return *(ushort_t*)&b; }

// Per-array dtype probe (first 16 words). Deterministic.
__device__ __forceinline__ bool probe_is_bf16(const void* p) {
    const unsigned int* w = (const unsigned int*)p;
    int nz = 0, band = 0;
    #pragma unroll
    for (int i = 0; i < 16; i++) {
        unsigned int v = w[i];
        if (v == 0u) continue;
        nz++;
        unsigned int lo = v & 0xFFFFu, hi = v >> 16;
        unsigned int elo = (lo >> 7) & 0xFFu, ehi = (hi >> 7) & 0xFFu;
        bool okl = (lo != 0u) && (elo >= 0x60u) && (elo <= 0x9Fu);
        bool okh = (hi != 0u) && (ehi >= 0x60u) && (ehi <= 0x9Fu);
        if (okl && okh) band++;
    }
    return (nz == 0) || (band == nz);
}

__device__ __forceinline__ float read_any(const void* p, size_t i, bool isb) {
    return isb ? toF(((const bf16*)p)[i]) : ((const float*)p)[i];
}

__device__ __forceinline__ float wave_sum(float v) {
    #pragma unroll
    for (int o = 1; o < 64; o <<= 1) v += __shfl_xor(v, o, 64);
    return v;
}

// ---------------- Fused canon of all 8 small fp32 params (1 launch) ----------------
__global__ void canon_small_kernel(const void* s0, const void* s1, const void* s2,
                                   const void* s3, const void* s4, const void* s5,
                                   const void* s6, const void* s7,
                                   float* __restrict__ cW) {
    const void* srcs[8] = {s0, s1, s2, s3, s4, s5, s6, s7};
    const int off[8]  = {0, 192, 361, 553, 745, 937, 1129, 1897};
    const int cnt[8]  = {192, 169, 192, 192, 192, 192, 768, 192};
    const int doff[8] = {0, 192, 384, 576, 768, 960, 1152, 1920};
    int i = blockIdx.x * 256 + threadIdx.x;
    if (i >= 2089) return;
    int s = 0;
    #pragma unroll
    for (int k = 1; k < 8; k++) if (i >= off[k]) s = k;
    int j = i - off[s];
    if (j < cnt[s]) {
        bool isb = probe_is_bf16(srcs[s]);
        cW[doff[s] + j] = read_any(srcs[s], j, isb);
    }
}

// ---------------- Fused canon+transpose of all 4 weights (1 launch) ----------------
__global__ void canon_bt4_kernel(const void* w0, const void* w1, const void* w2,
                                 const void* w3, ushort_t* __restrict__ cT) {
    int bid = blockIdx.x;
    const void* src; ushort_t* dst; int K, N, base;
    if (bid < 432)       { src = w0; dst = cT;          K = CDIM; N = QKVW; base = bid; }
    else if (bid < 576)  { src = w1; dst = cT + 110592; K = CDIM; N = CDIM; base = bid - 432; }
    else if (bid < 1152) { src = w2; dst = cT + 147456; K = CDIM; N = MLPW; base = bid - 576; }
    else                 { src = w3; dst = cT + 294912; K = MLPW; N = CDIM; base = bid - 1152; }
    int i = base * 256 + threadIdx.x;
    if (i < K * N) {
        bool isb = probe_is_bf16(src);
        int k = i / N, n = i % N;
        dst[(size_t)n * K + k] = f2u(read_any(src, i, isb));
    }
}

// ---------------- LN1: raw x (probed) -> bf16 ----------------
__global__ void ln1_kernel(const void* __restrict__ xraw, const float* __restrict__ g,
                           const float* __restrict__ bta, bf16* __restrict__ out) {
    bool xb = probe_is_bf16(xraw);
    int wave = threadIdx.x >> 6, lane = threadIdx.x & 63;
    int t = blockIdx.x * 4 + wave;
    size_t base = (size_t)t * CDIM;
    float v[3];
    #pragma unroll
    for (int i = 0; i < 3; i++) v[i] = read_any(xraw, base + lane + 64 * i, xb);
    float s  = v[0] + v[1] + v[2];
    float s2 = v[0]*v[0] + v[1]*v[1] + v[2]*v[2];
    s = wave_sum(s); s2 = wave_sum(s2);
    float mu = s * (1.0f / CDIM);
    float var = s2 * (1.0f / CDIM) - mu * mu;
    float rs = rsqrtf(var + 1e-5f);
    #pragma unroll
    for (int i = 0; i < 3; i++) {
        int c = lane + 64 * i;
        out[base + c] = f2b((v[i] - mu) * rs * g[c] + bta[c]);
    }
}

// ========== Reg-A MFMA GEMM for K=192 (A = bf16 token-major, no A-LDS) ==========
// A-fragment [l15=row][quad*8+j=k] loads directly from global (bf16x8/lane).
// B staged: 24 KB via global_load_lds w16 + both-sides XOR swizzle, issued
// first so latency hides under the A loads. ONE barrier. Wave owns 32 rows.
// EPI 0: plain bf16 store (qkv). EPI 1: +bias +probed-x residual -> bf16 (proj).
template <int EPI, int NY>
__global__ __launch_bounds__(256) void gemm192r_kernel(
    const ushort_t* __restrict__ A,  // bf16 [NTOK][192]
    const ushort_t* __restrict__ BT, // bf16 [N][192]
    const int N,
    const float* __restrict__ bias,
    const void* __restrict__ res,
    void* __restrict__ out)
{
    __shared__ ushort_t Bs[3][64 * 64];
    int tid = threadIdx.x;
    int per = gridDim.x >> 3;
    int sid = blockIdx.x;
    int w = (sid & 7) * per + (sid >> 3);
    int t0 = (w / NY) * 128;
    int n0 = (w % NY) * 64;
    int lane = tid & 63, wv = tid >> 6;
    int l15 = lane & 15, quad = lane >> 4;
    int lr = lane >> 3, lc = lane & 7;

    #pragma unroll
    for (int p = 0; p < 3; p++) {
        #pragma unroll
        for (int it = 0; it < 2; it++) {
            int r = wv * 16 + it * 8 + lr;                 // r&7 == lr
            const ushort_t* src = &BT[(size_t)(n0 + r) * 192 + p * 64 + ((lc ^ lr) << 3)];
            __builtin_amdgcn_global_load_lds(
                (gbl_void*)src, (lds_void*)&Bs[p][(wv * 16 + it * 8) * 64], 16, 0, 0);
        }
    }

    bf16x8 af[2][6];
    #pragma unroll
    for (int m = 0; m < 2; m++) {
        size_t rb = (size_t)(t0 + wv * 32 + m * 16 + l15) * CDIM;
        #pragma unroll
        for (int kk = 0; kk < 6; kk++)
            af[m][kk] = *(const bf16x8*)(A + rb + kk * 32 + quad * 8);
    }

    f32x4 acc[2][4];
    #pragma unroll
    for (int i = 0; i < 2; i++)
        #pragma unroll
        for (int j = 0; j < 4; j++)
            acc[i][j] = (f32x4){0.f, 0.f, 0.f, 0.f};

    __syncthreads();    // Bs resident

    #pragma unroll
    for (int kk = 0; kk < 6; kk++) {
        int p = kk >> 1;
        int cs = ((((kk & 1) * 4 + quad)) ^ (l15 & 7)) << 3;
        bf16x8 bfr[4];
        #pragma unroll
        for (int j = 0; j < 4; j++)
            bfr[j] = *(const bf16x8*)(&Bs[p][(j * 16 + l15) * 64 + cs]);
        #pragma unroll
        for (int i = 0; i < 2; i++)
            #pragma unroll
            for (int j = 0; j < 4; j++)
                acc[i][j] = __builtin_amdgcn_mfma_f32_16x16x32_bf16(af[i][kk], bfr[j], acc[i][j], 0, 0, 0);
    }

    bool xb = false;
    if (EPI == 1) xb = probe_is_bf16(res);

    #pragma unroll
    for (int i = 0; i < 2; i++) {
        #pragma unroll
        for (int j = 0; j < 4; j++) {
            #pragma unroll
            for (int r = 0; r < 4; r++) {
                int row = wv * 32 + i * 16 + quad * 4 + r;
                int col = n0 + j * 16 + l15;
                size_t t = (size_t)(t0 + row);
                float v = acc[i][j][r];
                if (EPI == 0) {
                    ((bf16*)out)[t * N + col] = f2b(v);
                } else {
                    size_t o = t * CDIM + col;
                    ((bf16*)out)[o] = f2b(v + bias[col] + read_any(res, o, xb));
                }
            }
        }
    }
}

// ================= Fused LN2 + MLP1(+GELU) + MLP2 (+residual), v6 =================
// Round-4 shell (block = 256 thr = 4 waves = 128 tokens, wave owns 32 rows,
// LDS 64 KB, 2 blocks/CU, (256,2)). Round-9 changes:
//  (a) gemm1 SWAPPED operands: haccT = mfma(bfr, af) puts 4 CONSECUTIVE hidden
//      cols per thread (row=hid quad*4+r, col=tok l15) -> Hs spill becomes 8
//      packed 8B stores/thread/chunk instead of 32 scalar b16 (write-side
//      swizzle formula becomes identical to gemm2's read side). gemm2 unchanged.
//  (b) GELU divide 2/(e+1) -> __builtin_amdgcn_rcpf (exact IEEE div was ~12
//      VALU ops since no -ffast-math; rcp is 1 op, ~1ulp, invisible in bf16).
__global__ __launch_bounds__(256, 2) void fused_mlp_kernel(
    const bf16* __restrict__ X,        // [NTOK][192] bf16 (pre-LN residual = x1)
    const ushort_t* __restrict__ W1T,  // [768][192]
    const ushort_t* __restrict__ W2T,  // [192][768]
    const float* __restrict__ g, const float* __restrict__ bta,
    const float* __restrict__ b1, const float* __restrict__ b2,
    float* __restrict__ out)
{
    __shared__ ushort_t W1s[3 * 64 * 64];   // (24 KB)
    __shared__ ushort_t W2s[192 * 64];      // (24 KB)
    __shared__ ushort_t Hs[128 * 64];       // (16 KB) [tok][hid], swizzled
    int tid = threadIdx.x;
    int lane = tid & 63, wv = tid >> 6;     // wv 0..3
    int l15 = lane & 15, quad = lane >> 4;
    int lr = lane >> 3, lc = lane & 7;
    int t0 = blockIdx.x * 128;

    auto stageW1 = [&](int c) {
        #pragma unroll
        for (int p = 0; p < 3; p++)
            #pragma unroll
            for (int rg = 0; rg < 2; rg++) {
                int rowb = wv * 16 + rg * 8;
                const ushort_t* src =
                    &W1T[(size_t)(c * 64 + rowb + lr) * CDIM + p * 64 + ((lc ^ lr) << 3)];
                __builtin_amdgcn_global_load_lds(
                    (gbl_void*)src, (lds_void*)&W1s[p * 4096 + rowb * 64], 16, 0, 0);
            }
    };
    auto stageW2 = [&](int c) {
        #pragma unroll
        for (int rg = 0; rg < 6; rg++) {
            int rowb = wv * 48 + rg * 8;
            const ushort_t* src =
                &W2T[(size_t)(rowb + lr) * MLPW + c * 64 + ((lc ^ lr) << 3)];
            __builtin_amdgcn_global_load_lds(
                (gbl_void*)src, (lds_void*)&W2s[rowb * 64], 16, 0, 0);
        }
    };

    stageW1(0);
    stageW2(0);

    // ---- LN2 into register A-fragments, in place (wave's 2 x 16 rows) ----
    bf16x8 af[2][6];
    float s[2] = {0.f, 0.f}, s2[2] = {0.f, 0.f};
    #pragma unroll
    for (int m = 0; m < 2; m++) {
        size_t rb = (size_t)(t0 + wv * 32 + m * 16 + l15) * CDIM;
        #pragma unroll
        for (int kk = 0; kk < 6; kk++) {
            af[m][kk] = *(const bf16x8*)((const ushort_t*)X + rb + kk * 32 + quad * 8);
            #pragma unroll
            for (int j = 0; j < 8; j++) {
                float f = (float)af[m][kk][j];
                s[m] += f; s2[m] += f * f;
            }
        }
    }
    #pragma unroll
    for (int m = 0; m < 2; m++) {
        s[m]  += __shfl_xor(s[m], 16, 64);  s[m]  += __shfl_xor(s[m], 32, 64);
        s2[m] += __shfl_xor(s2[m], 16, 64); s2[m] += __shfl_xor(s2[m], 32, 64);
    }
    #pragma unroll
    for (int kk = 0; kk < 6; kk++) {
        int c0 = kk * 32 + quad * 8;
        float4 g0 = *(const float4*)(g + c0), g1 = *(const float4*)(g + c0 + 4);
        float4 b0 = *(const float4*)(bta + c0), b1v = *(const float4*)(bta + c0 + 4);
        const float* gp[2] = {&g0.x, &g1.x};
        const float* bp[2] = {&b0.x, &b1v.x};
        #pragma unroll
        for (int m = 0; m < 2; m++) {
            float mu = s[m] * (1.0f / CDIM);
            float var = s2[m] * (1.0f / CDIM) - mu * mu;
            float rs = rsqrtf(var + 1e-5f);
            #pragma unroll
            for (int j = 0; j < 8; j++)
                af[m][kk][j] = (__bf16)(((float)af[m][kk][j] - mu) * rs * gp[j >> 2][j & 3]
                                        + bp[j >> 2][j & 3]);
        }
    }

    f32x4 acc2[2][12];
    #pragma unroll
    for (int m = 0; m < 2; m++)
        #pragma unroll
        for (int nt = 0; nt < 12; nt++) acc2[m][nt] = (f32x4){0.f, 0.f, 0.f, 0.f};

    __syncthreads();                        // chunk-0 weights resident

    for (int c = 0; c < 12; c++) {
        // ---- gemm1 (swapped): haccT[j][m] row=hid(j*16+quad*4+r) col=tok(m*16+l15) ----
        f32x4 haccT[4][2];
        #pragma unroll
        for (int j = 0; j < 4; j++)
            #pragma unroll
            for (int m = 0; m < 2; m++) haccT[j][m] = (f32x4){0.f, 0.f, 0.f, 0.f};
        #pragma unroll
        for (int kk = 0; kk < 6; kk++) {
            int p = kk >> 1;
            int cc = (kk & 1) * 4 + quad;
            #pragma unroll
            for (int j = 0; j < 4; j++) {
                int n = j * 16 + l15;
                bf16x8 bfr = *(const bf16x8*)(&W1s[p * 4096 + n * 64 + ((cc ^ (n & 7)) << 3)]);
                #pragma unroll
                for (int m = 0; m < 2; m++)
                    haccT[j][m] = __builtin_amdgcn_mfma_f32_16x16x32_bf16(bfr, af[m][kk], haccT[j][m], 0, 0, 0);
            }
        }
        // ---- +b1, tanh-GELU (rcp form), packed 8B -> Hs[tok][hid] ----
        #pragma unroll
        for (int j = 0; j < 4; j++) {
            float4 bb = *(const float4*)(b1 + c * 64 + j * 16 + quad * 4);
            const float* bbp = &bb.x;
            #pragma unroll
            for (int m = 0; m < 2; m++) {
                ushort_t hv[4];
                #pragma unroll
                for (int r = 0; r < 4; r++) {
                    float a = haccT[j][m][r] + bbp[r];
                    float yv = 0.7978845608028654f * (a + 0.044715f * a * a * a);
                    float th = 1.0f - 2.0f * __builtin_amdgcn_rcpf(__expf(2.0f * yv) + 1.0f);
                    hv[r] = f2u(0.5f * a * (1.0f + th));
                }
                int tok = wv * 32 + m * 16 + l15;
                int hid = j * 16 + quad * 4;
                unsigned int u0 = (unsigned int)hv[0] | ((unsigned int)hv[1] << 16);
                unsigned int u1 = (unsigned int)hv[2] | ((unsigned int)hv[3] << 16);
                *(uint2*)(&Hs[tok * 64 + (((hid >> 3) ^ (tok & 7)) << 3) + (hid & 7)]) =
                    make_uint2(u0, u1);
            }
        }
        __syncthreads();                    // B1: Hs ready, W1s free, drains W2(c)

        if (c + 1 < 12) stageW1(c + 1);     // hides under gemm2

        // ---- gemm2: acc2 += Hs @ W2c^T (read path unchanged) ----
        #pragma unroll
        for (int kt = 0; kt < 2; kt++) {
            int cc = kt * 4 + quad;
            bf16x8 pa[2];
            #pragma unroll
            for (int m = 0; m < 2; m++) {
                int row = wv * 32 + m * 16 + l15;
                pa[m] = *(const bf16x8*)(&Hs[row * 64 + ((cc ^ (row & 7)) << 3)]);
            }
            #pragma unroll
            for (int nt = 0; nt < 12; nt++) {
                int n = nt * 16 + l15;
                bf16x8 wb = *(const bf16x8*)(&W2s[n * 64 + ((cc ^ (n & 7)) << 3)]);
                #pragma unroll
                for (int m = 0; m < 2; m++)
                    acc2[m][nt] = __builtin_amdgcn_mfma_f32_16x16x32_bf16(pa[m], wb, acc2[m][nt], 0, 0, 0);
            }
        }
        __syncthreads();                    // B2: W2s+Hs free, drains W1(c+1)

        if (c + 1 < 12) stageW2(c + 1);     // drained at next B1
    }

    #pragma unroll
    for (int nt = 0; nt < 12; nt++) {
        float bb = b2[nt * 16 + l15];
        #pragma unroll
        for (int m = 0; m < 2; m++) {
            #pragma unroll
            for (int r = 0; r < 4; r++) {
                int row = t0 + wv * 32 + m * 16 + quad * 4 + r;
                int col = nt * 16 + l15;
                size_t o = (size_t)row * CDIM + col;
                out[o] = acc2[m][nt][r] + bb + toF(X[o]);
            }
        }
    }
}

// ================= MFMA window attention =================
// 1 wave = 1 (batch, window, head). Swapped PV -> O^T, 8B packed stores.
// Softmax 1/sum via v_rcp (exact div was ~12 VALU ops).
__global__ __launch_bounds__(256) void attn_kernel(const bf16* __restrict__ qkv,
                                                   const float* __restrict__ pos_emb,
                                                   bf16* __restrict__ y) {
    __shared__ ushort_t Ps[4][64 * 72];
    __shared__ ushort_t Vt[4][32 * 72];
    __shared__ float pe[169];

    int tid = threadIdx.x;
    int wv = tid >> 6, lane = tid & 63;
    int l15 = lane & 15, quad = lane >> 4;

    int per = gridDim.x >> 3;
    int sid = blockIdx.x;
    int bid = (sid & 7) * per + (sid >> 3);
    int gid = bid * 4 + wv;
    int h = gid % HEADS;
    int rest = gid / HEADS;
    int win = rest % NWIN;
    int b = rest / NWIN;
    int wi = win >> 4, wj = win & 15;

    for (int i = lane; i < 169; i += 64) pe[i] = pos_emb[i];
    __syncthreads();

    auto tok = [&](int i) -> int {
        i = min(i, 48);
        int pi = (i * 37) >> 8;
        int pj = i - pi * 7;
        int ui = wi * WS + pi + 3; if (ui >= HH) ui -= HH;
        int uj = wj * WS + pj + 3; if (uj >= WW) uj -= WW;
        return (b * HH + ui) * WW + uj;
    };

    bf16x8 qf[4], kf[4];
    #pragma unroll
    for (int t = 0; t < 4; t++) {
        size_t base = (size_t)tok(t * 16 + l15) * QKVW + h * HD + quad * 8;
        qf[t] = *(const bf16x8*)(qkv + base);
        kf[t] = *(const bf16x8*)(qkv + base + CDIM);
    }

    #pragma unroll
    for (int it = 0; it < 4; it++) {
        int idx = lane + it * 64;
        int p = idx >> 2, dc = idx & 3;
        size_t base = (size_t)tok(p) * QKVW + 2 * CDIM + h * HD + dc * 8;
        ushortx8 v = *(const ushortx8*)((const ushort_t*)qkv + base);
        #pragma unroll
        for (int jj = 0; jj < 8; jj++)
            Vt[wv][(dc * 8 + jj) * 72 + p] = v[jj];
    }

    f32x4 acc[4][4];
    #pragma unroll
    for (int mt = 0; mt < 4; mt++)
        #pragma unroll
        for (int nt = 0; nt < 4; nt++)
            acc[mt][nt] = (f32x4){0.f, 0.f, 0.f, 0.f};
    #pragma unroll
    for (int mt = 0; mt < 4; mt++)
        #pragma unroll
        for (int nt = 0; nt < 4; nt++)
            acc[mt][nt] = __builtin_amdgcn_mfma_f32_16x16x32_bf16(qf[mt], kf[nt], acc[mt][nt], 0, 0, 0);

    bool m_ul = (wi == NWH - 1);
    bool m_lr = (wj == NWW - 1);
    int kpi[4], kpj[4];
    bool jval[4];
    #pragma unroll
    for (int nt = 0; nt < 4; nt++) {
        int j = nt * 16 + l15;
        jval[nt] = (j < WS2);
        int jc = min(j, 48);
        kpi[nt] = (jc * 37) >> 8;
        kpj[nt] = jc - kpi[nt] * 7;
    }
    #pragma unroll
    for (int mt = 0; mt < 4; mt++) {
        #pragma unroll
        for (int r = 0; r < 4; r++) {
            int i = mt * 16 + quad * 4 + r;
            int ic = min(i, 48);
            int pi = (ic * 37) >> 8;
            int pj = ic - pi * 7;
            #pragma unroll
            for (int nt = 0; nt < 4; nt++) {
                float s = acc[mt][nt][r] * 0.17677669529663689f
                        + pe[(pi - kpi[nt] + 6) * 13 + (pj - kpj[nt] + 6)];
                if (m_ul && ((pi >= 4) != (kpi[nt] >= 4))) s += NEGV;
                if (m_lr && ((pj >= 4) != (kpj[nt] >= 4))) s += NEGV;
                if (!jval[nt]) s = NEGV;
                acc[mt][nt][r] = s;
            }
            float mx = fmaxf(fmaxf(acc[mt][0][r], acc[mt][1][r]),
                             fmaxf(acc[mt][2][r], acc[mt][3][r]));
            #pragma unroll
            for (int o = 1; o < 16; o <<= 1) mx = fmaxf(mx, __shfl_xor(mx, o, 64));
            float sum = 0.f;
            #pragma unroll
            for (int nt = 0; nt < 4; nt++) {
                float e = __expf(acc[mt][nt][r] - mx);
                acc[mt][nt][r] = e;
                sum += e;
            }
            #pragma unroll
            for (int o = 1; o < 16; o <<= 1) sum += __shfl_xor(sum, o, 64);
            float inv = __builtin_amdgcn_rcpf(sum);   // sum >= 1, ~1ulp
            #pragma unroll
            for (int nt = 0; nt < 4; nt++) acc[mt][nt][r] *= inv;
        }
    }

    #pragma unroll
    for (int mt = 0; mt < 4; mt++)
        #pragma unroll
        for (int nt = 0; nt < 4; nt++)
            #pragma unroll
            for (int r = 0; r < 4; r++)
                Ps[wv][(mt * 16 + quad * 4 + r) * 72 + nt * 16 + l15] = f2u(acc[mt][nt][r]);

    // ---- O^T = mfma(Vt-frag, Ps-frag): row=d (dt tiles), col=i (it tiles) ----
    f32x4 oaccT[2][4];
    #pragma unroll
    for (int dt = 0; dt < 2; dt++)
        #pragma unroll
        for (int it = 0; it < 4; it++)
            oaccT[dt][it] = (f32x4){0.f, 0.f, 0.f, 0.f};
    #pragma unroll
    for (int kt = 0; kt < 2; kt++) {
        bf16x8 pa[4], vb[2];
        #pragma unroll
        for (int it = 0; it < 4; it++)
            pa[it] = *(const bf16x8*)(&Ps[wv][(it * 16 + l15) * 72 + kt * 32 + quad * 8]);
        #pragma unroll
        for (int dt = 0; dt < 2; dt++)
            vb[dt] = *(const bf16x8*)(&Vt[wv][(dt * 16 + l15) * 72 + kt * 32 + quad * 8]);
        #pragma unroll
        for (int dt = 0; dt < 2; dt++)
            #pragma unroll
            for (int it = 0; it < 4; it++)
                oaccT[dt][it] = __builtin_amdgcn_mfma_f32_16x16x32_bf16(vb[dt], pa[it], oaccT[dt][it], 0, 0, 0);
    }

    #pragma unroll
    for (int it = 0; it < 4; it++) {
        int i = it * 16 + l15;
        if (i < WS2) {
            size_t base = (size_t)tok(i) * CDIM + h * HD + quad * 4;
            #pragma unroll
            for (int dt = 0; dt < 2; dt++) {
                unsigned int u0 = (unsigned int)f2u(oaccT[dt][it][0])
                                | ((unsigned int)f2u(oaccT[dt][it][1]) << 16);
                unsigned int u1 = (unsigned int)f2u(oaccT[dt][it][2])
                                | ((unsigned int)f2u(oaccT[dt][it][3]) << 16);
                *(uint2*)((ushort_t*)y + base + dt * 16) = make_uint2(u0, u1);
            }
        }
    }
}

extern "C" void kernel_launch(void* const* d_in, const int* in_sizes, int n_in,
                              void* d_out, int out_size, void* d_ws, size_t ws_size,
                              hipStream_t stream) {
    float* out = (float*)d_out;   // reference output dtype: float32

    size_t szA = (size_t)NTOK * CDIM * sizeof(bf16);
    size_t szQ = (size_t)NTOK * QKVW * sizeof(bf16);
    size_t szY = (size_t)NTOK * CDIM * sizeof(bf16);
    size_t szX = (size_t)NTOK * CDIM * sizeof(bf16);
    size_t szP = 3072 * sizeof(float);
    size_t szT = 442368 * sizeof(ushort_t);
    if (ws_size < szA + szQ + szY + szX + szP + szT) return;
    bf16*     bufA = (bf16*)d_ws;
    bf16*     bufQ = (bf16*)((char*)d_ws + szA);
    bf16*     bufY = (bf16*)((char*)d_ws + szA + szQ);
    bf16*     bufX = (bf16*)((char*)d_ws + szA + szQ + szY);
    float*    cW   = (float*)((char*)d_ws + szA + szQ + szY + szX);
    ushort_t* cT   = (ushort_t*)((char*)d_ws + szA + szQ + szY + szX + szP);

    float* cBout = cW + 0;      // 192
    float* cPe   = cW + 192;    // 169
    float* cL1g  = cW + 384;
    float* cL1b  = cW + 576;
    float* cL2g  = cW + 768;
    float* cL2b  = cW + 960;
    float* cB1   = cW + 1152;   // 768
    float* cB2   = cW + 1920;   // 192

    ushort_t* tWqkv = cT + 0;        // [576][192]
    ushort_t* tWout = cT + 110592;   // [192][192]
    ushort_t* tW1   = cT + 147456;   // [768][192]
    ushort_t* tW2   = cT + 294912;   // [192][768]

    dim3 b256(256);
    canon_small_kernel<<<9, b256, 0, stream>>>(
        d_in[3], d_in[4], d_in[5], d_in[6], d_in[7], d_in[8], d_in[10], d_in[12], cW);
    canon_bt4_kernel<<<1728, b256, 0, stream>>>(
        d_in[1], d_in[2], d_in[9], d_in[11], cT);

    int gLN = NTOK / 4;                 // 25088
    int gM  = NTOK / 128;               // 784
    int gAT = BATCH * NWIN * HEADS / 4; // 3072 blocks, 4 window-heads each
    int gF  = NTOK / 128;               // 784

    ln1_kernel<<<gLN, b256, 0, stream>>>(d_in[0], cL1g, cL1b, bufA);
    gemm192r_kernel<0, 9><<<gM * 9, b256, 0, stream>>>(
        (const ushort_t*)bufA, tWqkv, QKVW, nullptr, nullptr, bufQ);
    attn_kernel<<<gAT, b256, 0, stream>>>(bufQ, cPe, bufY);
    gemm192r_kernel<1, 3><<<gM * 3, b256, 0, stream>>>(
        (const ushort_t*)bufY, tWout, CDIM, cBout, d_in[0], bufX);
    fused_mlp_kernel<<<gF, b256, 0, stream>>>(
        bufX, tW1, tW2, cL2g, cL2b, cB1, cB2, out);
}